// Round 8
// baseline (313.599 us; speedup 1.0000x reference)
//
#include <hip/hip_runtime.h>
#include <hip/hip_bf16.h>
#include <stdint.h>

typedef int i32x4 __attribute__((ext_vector_type(4)));

// ---------------- exact-math helpers (match XLA/np f32 semantics) -----------

__device__ __forceinline__ float xla_erf(float x) {
#pragma clang fp contract(off)
  x = fminf(3.832506856900711f, fmaxf(-3.832506856900711f, x));
  float x2 = x * x;
  float p = -2.72614225801306e-10f;
  p = p * x2 + 2.77068142495902e-08f;
  p = p * x2 + -2.10102402082508e-06f;
  p = p * x2 + -5.69250639462346e-05f;
  p = p * x2 + -7.34990630326855e-04f;
  p = p * x2 + -2.95459980854025e-03f;
  p = p * x2 + -1.60960333262415e-02f;
  p = x * p;
  float q = -1.45660718464996e-05f;
  q = q * x2 + -2.13374055278905e-04f;
  q = q * x2 + -1.68282697438203e-03f;
  q = q * x2 + -7.37332916720468e-03f;
  q = q * x2 + -1.42647390514189e-02f;
  return p / q;
}

__device__ __forceinline__ float gelu_exact(float x) {
#pragma clang fp contract(off)
  float t = x / 1.41421356237309504880f;
  float e = xla_erf(t);
  float u = e + 1.0f;
  float v = x * u;
  return v * 0.5f;
}

__device__ __forceinline__ float epi_scale(float iacc, float sc, float b) {
#pragma clang fp contract(off)
  float v = iacc * sc;
  v = v + b;
  return v;
}

__device__ __forceinline__ int quant1(float x, float scale) {
#pragma clang fp contract(off)
  float t = x / scale;
  t = rintf(t);
  t = fmaxf(-8.0f, fminf(7.0f, t));
  return (int)t;
}

// ---------------- small kernels ---------------------------------------------

__global__ void init_kernel(unsigned* slots) {
  if (threadIdx.x < 4) slots[threadIdx.x] = 0u;
}

__global__ void absmax3(const float* __restrict__ p0, long n0,
                        const float* __restrict__ p1, long n1,
                        const float* __restrict__ p2, long n2,
                        unsigned* __restrict__ slots) {
  const int t = blockIdx.y;
  const float4* p = (const float4*)(t == 0 ? p0 : (t == 1 ? p1 : p2));
  const long n4 = (t == 0 ? n0 : (t == 1 ? n1 : n2));
  float m = 0.0f;
  long i = (long)blockIdx.x * blockDim.x + threadIdx.x;
  const long stride = (long)gridDim.x * blockDim.x;
  for (; i < n4; i += stride) {
    float4 v = p[i];
    m = fmaxf(m, fmaxf(fmaxf(fabsf(v.x), fabsf(v.y)), fmaxf(fabsf(v.z), fabsf(v.w))));
  }
  for (int o = 32; o > 0; o >>= 1) m = fmaxf(m, __shfl_xor(m, o));
  if ((threadIdx.x & 63) == 0) atomicMax(slots + t, __float_as_uint(m));
}

// fp32 [R][C] -> signed i8 [Rpad][ldq] (row-major); bytes [C, C+segs) hold the
// per-segment signed AND-mask (sign=-1 for weights); [C+segs, ldq) zero.
__global__ void quant_kernel(const float* __restrict__ in, int R, int C, int ldq,
                             const unsigned* __restrict__ slot, int sign,
                             char* __restrict__ qout) {
  const int segs_per_row = C >> 8;
  const int seg = blockIdx.x * 4 + (threadIdx.x >> 6);
  const int lane = threadIdx.x & 63;
  const int r = seg / segs_per_row;
  const int s = seg - r * segs_per_row;
  const float scale = fmaxf(__uint_as_float(*slot) / 7.0f, 1e-8f);
  const size_t qbase = (size_t)r * ldq + (size_t)s * 256 + lane * 4;
  int mask = 0;
  if (r < R) {
    const size_t base = (size_t)r * C + (size_t)s * 256 + lane * 4;
    float4 v = *(const float4*)(in + base);
    int q0 = quant1(v.x, scale);
    int q1 = quant1(v.y, scale);
    int q2 = quant1(v.z, scale);
    int q3 = quant1(v.w, scale);
    unsigned pk = (q0 & 0xff) | ((q1 & 0xff) << 8) | ((q2 & 0xff) << 16) |
                  ((unsigned)(q3 & 0xff) << 24);
    *(unsigned*)(qout + qbase) = pk;
    mask = q0 & q1 & q2 & q3 & 15;
  } else {
    *(unsigned*)(qout + qbase) = 0u;
    mask = 0;
  }
  for (int o = 32; o > 0; o >>= 1) mask &= __shfl_xor(mask, o);
  if (lane == 0)
    qout[(size_t)r * ldq + C + s] = (char)(sign * ((mask & 7) - (mask & 8)));
  const int padw = ldq - C - segs_per_row;
  if (s == 0 && lane < padw)
    qout[(size_t)r * ldq + C + segs_per_row + lane] = 0;
}

// ---------------- GEMM core: MFMA only, fragment-order i32x4 stores ----------
// 128x128 tile, 4 waves (2x2), i8 K=64 fragments loaded register-direct
// (pattern verified rounds 5-7). NO epilogue math: acc written raw as one
// dwordx4 per fragment, lane-contiguous (streaming-class store pattern).
// blockIdx.y = split-K chunk; chunk c writes to frag + c*cslots.
__global__ __launch_bounds__(256) void gemm_frag(
    const char* __restrict__ A, const char* __restrict__ B,
    int ldq, int mtiles, int kbase, int krem,
    i32x4* __restrict__ frag, long cslots) {
  const int tid = threadIdx.x;
  const int lane = tid & 63;
  const int wv = tid >> 6;

  // bijective XCD-aware swizzle (m204)
  const int nwg = gridDim.x;
  const int q8 = nwg >> 3, r8 = nwg & 7;
  const int xcd = blockIdx.x & 7, idx = blockIdx.x >> 3;
  const int sw = (xcd < r8 ? xcd * (q8 + 1) : r8 * (q8 + 1) + (xcd - r8) * q8) + idx;
  const int bm = sw % mtiles;
  const int bn = sw / mtiles;
  const long m0 = (long)bm * 128;
  const long n0 = (long)bn * 128;
  const int chunk = blockIdx.y;
  const int k_begin = chunk * kbase + min(chunk, krem);  // BK=64 units
  const int k_iters = kbase + (chunk < krem ? 1 : 0);

  const int wm = wv >> 1, wn = wv & 1;
  const int lr = lane & 15, kg = lane >> 4;

  const char* pA = A + (m0 + wm * 64 + lr) * (long)ldq + (long)k_begin * 64 + kg * 16;
  const char* pB = B + (n0 + wn * 64 + lr) * (long)ldq + (long)k_begin * 64 + kg * 16;
  const long fstride = 16 * (long)ldq;

  i32x4 acc[4][4] = {};

#pragma unroll 2
  for (int kt = 0; kt < k_iters; ++kt) {
    const long ko = (long)kt * 64;
    i32x4 av[4], bv[4];
#pragma unroll
    for (int f = 0; f < 4; ++f) av[f] = *(const i32x4*)(pA + f * fstride + ko);
#pragma unroll
    for (int f = 0; f < 4; ++f) bv[f] = *(const i32x4*)(pB + f * fstride + ko);
#pragma unroll
    for (int fa = 0; fa < 4; ++fa)
#pragma unroll
      for (int fb = 0; fb < 4; ++fb)
        acc[fa][fb] = __builtin_amdgcn_mfma_i32_16x16x64_i8(av[fa], bv[fb], acc[fa][fb], 0, 0, 0);
  }

  i32x4* po = frag + (long)chunk * cslots + (((long)sw * 4 + wv) * 16) * 64 + lane;
#pragma unroll
  for (int fa = 0; fa < 4; ++fa)
#pragma unroll
    for (int fb = 0; fb < 4; ++fb)
      po[(fa * 4 + fb) * 64] = acc[fa][fb];  // global_store_dwordx4, coalesced
}

// decode helper: fragment-slot t -> (m base, n); layout matches gemm_frag
struct Dec { long mb; long n; };
__device__ __forceinline__ Dec frag_decode(long t, int mtiles) {
  const int slot = (int)(t >> 12);
  const int r = (int)t & 4095;
  const int wv = r >> 10, fafb = (r >> 6) & 15, lane = r & 63;
  const int fa = fafb >> 2, fb = fafb & 3;
  const int wm = wv >> 1, wn = wv & 1;
  const int kg = lane >> 4, lr = lane & 15;
  const int bm = slot % mtiles, bn = slot / mtiles;
  Dec d;
  d.mb = (long)bm * 128 + wm * 64 + fa * 16 + kg * 4;  // rows mb..mb+3
  d.n = (long)bn * 128 + wn * 64 + fb * 16 + lr;
  return d;
}

// pass A: h = gelu(frag*sc + b1); global absmax(h) -> slots[3]
__global__ void epi1max(const i32x4* __restrict__ frag, long nfrag, int mtiles,
                        int Mstore, const float* __restrict__ b1,
                        const unsigned* __restrict__ slots) {
  __shared__ float red[4];
  const long t = (long)blockIdx.x * 256 + threadIdx.x;
  const float sa = fmaxf(__uint_as_float(slots[0]) / 7.0f, 1e-8f);
  const float sb = fmaxf(__uint_as_float(slots[1]) / 7.0f, 1e-8f);
  const float sc = sa * sb;
  float hmax = 0.0f;
  if (t < nfrag) {
    Dec d = frag_decode(t, mtiles);
    i32x4 v = frag[t];
    const float b = b1[d.n];
#pragma unroll
    for (int rr = 0; rr < 4; ++rr) {
      if (d.mb + rr < Mstore) {
        float h = gelu_exact(epi_scale((float)v[rr], sc, b));
        hmax = fmaxf(hmax, fabsf(h));
      }
    }
  }
  for (int o = 32; o > 0; o >>= 1) hmax = fmaxf(hmax, __shfl_xor(hmax, o));
  if ((threadIdx.x & 63) == 0) red[threadIdx.x >> 6] = hmax;
  __syncthreads();
  if (threadIdx.x == 0) {
    float m = fmaxf(fmaxf(red[0], red[1]), fmaxf(red[2], red[3]));
    atomicMax((unsigned*)slots + 3, __float_as_uint(m));
  }
}

// pass B: recompute h, quantize -> hq (row-major i8), AND-mask -> table
__global__ void epi1quant(const i32x4* __restrict__ frag, long nfrag, int mtiles,
                          int Mstore, const float* __restrict__ b1,
                          const unsigned* __restrict__ slots,
                          char* __restrict__ hq, int ldq,
                          unsigned* __restrict__ table, int nseg) {
  const long t = (long)blockIdx.x * 256 + threadIdx.x;
  if (t >= nfrag) return;
  const float sa = fmaxf(__uint_as_float(slots[0]) / 7.0f, 1e-8f);
  const float sb = fmaxf(__uint_as_float(slots[1]) / 7.0f, 1e-8f);
  const float sc = sa * sb;
  const float sh = fmaxf(__uint_as_float(slots[3]) / 7.0f, 1e-8f);
  Dec d = frag_decode(t, mtiles);
  i32x4 v = frag[t];
  const float b = b1[d.n];
  const int seg = (int)(d.n >> 8);
  const int lr = (int)threadIdx.x & 15;
#pragma unroll
  for (int rr = 0; rr < 4; ++rr) {
    const long m = d.mb + rr;
    const bool live = m < Mstore;
    int q = 0;
    if (live) {
      float h = gelu_exact(epi_scale((float)v[rr], sc, b));
      q = quant1(h, sh);
      hq[m * (long)ldq + d.n] = (char)q;
    }
    int msk = live ? (q & 15) : 15;
    // AND across the 16 lanes (lr) sharing (row, seg)
    msk &= __shfl_xor(msk, 1);
    msk &= __shfl_xor(msk, 2);
    msk &= __shfl_xor(msk, 4);
    msk &= __shfl_xor(msk, 8);
    if (live && lr == 0)
      atomicAnd(table + m * nseg + seg, 0xFFFFFFF0u | (unsigned)msk);
  }
}

// fill hq correction/tail columns [C, C+64) from table (sign = +1)
__global__ void tail_fill(const unsigned* __restrict__ table, int nseg,
                          char* __restrict__ hq, int ldq, int C) {
  const int t = blockIdx.x * 256 + threadIdx.x;
  const int r = t >> 6, j = t & 63;
  char v = 0;
  if (j < nseg) {
    unsigned u = table[r * nseg + j] & 15u;
    v = (char)((int)(u & 7) - (int)(u & 8));
  }
  hq[(long)r * ldq + C + j] = v;
}

// final epilogue: exact int sum of 4 split-K fragment chunks, scale+bias
__global__ void epi2frag(const i32x4* __restrict__ frag, long cslots, int mtiles,
                         int Mstore, const float* __restrict__ b2,
                         const unsigned* __restrict__ slots,
                         float* __restrict__ out, int ldo) {
  const long t = (long)blockIdx.x * 256 + threadIdx.x;
  if (t >= cslots) return;
  const float sa = fmaxf(__uint_as_float(slots[3]) / 7.0f, 1e-8f);
  const float sb = fmaxf(__uint_as_float(slots[2]) / 7.0f, 1e-8f);
  const float sc = sa * sb;
  Dec d = frag_decode(t, mtiles);
  i32x4 c0 = frag[t];
  i32x4 c1 = frag[t + cslots];
  i32x4 c2 = frag[t + 2 * cslots];
  i32x4 c3 = frag[t + 3 * cslots];
  const float b = b2[d.n];
#pragma unroll
  for (int rr = 0; rr < 4; ++rr) {
    const long m = d.mb + rr;
    if (m < Mstore) {
      int s = (c0[rr] + c1[rr]) + (c2[rr] + c3[rr]);  // exact ints
      out[m * (long)ldo + d.n] = epi_scale((float)s, sc, b);
    }
  }
}

// ---------------- launch -----------------------------------------------------

extern "C" void kernel_launch(void* const* d_in, const int* in_sizes, int n_in,
                              void* d_out, int out_size, void* d_ws, size_t ws_size,
                              hipStream_t stream) {
  const float* x  = (const float*)d_in[0];
  const float* w1 = (const float*)d_in[1];
  const float* b1 = (const float*)d_in[2];
  const float* w2 = (const float*)d_in[3];
  const float* b2 = (const float*)d_in[4];
  float* out = (float*)d_out;

  const int Ntok = 16 * 197;  // 3152
  const int Mpad = 3328;      // 26 tiles of 128
  const int D = 768, H = 3072;
  const int ldq1 = 832;       // 13 BK=64 iters
  const int ldq2 = 3136;      // 49 iters
  const int SPLITK = 4;       // 49 = 4*12 + 1
  const int MT = Mpad / 128;  // 26
  const long NF1 = (long)MT * (H / 128) * 4096;   // GEMM1 fragment lanes
  const long CS2 = (long)MT * (D / 128) * 4096;   // GEMM2 slots per chunk

  char* ws = (char*)d_ws;
  size_t o = 0;
  unsigned* slots = (unsigned*)(ws + o); o += 256;  // [x, w1, w2, h]
  char* xq  = ws + o; o += (size_t)Mpad * ldq1;
  char* wq1 = ws + o; o += (size_t)H * ldq1;
  char* wq2 = ws + o; o += (size_t)D * ldq2;
  char* hq  = ws + o; o += (size_t)Mpad * ldq2;
  o = (o + 255) & ~(size_t)255;
  unsigned* table = (unsigned*)(ws + o); o += (size_t)Mpad * 12 * 4;
  o = (o + 255) & ~(size_t)255;
  i32x4* frag = (i32x4*)(ws + o); o += (size_t)NF1 * 16;  // 40.9 MB, reused by GEMM2
  (void)ws_size; (void)in_sizes; (void)n_in; (void)out_size;

  hipLaunchKernelGGL(init_kernel, dim3(1), dim3(64), 0, stream, slots);
  hipMemsetAsync(table, 0xFF, (size_t)Mpad * 12 * 4, stream);

  hipLaunchKernelGGL(absmax3, dim3(512, 3), dim3(256), 0, stream,
                     x, (long)Ntok * D / 4, w1, (long)H * D / 4,
                     w2, (long)D * H / 4, slots);

  hipLaunchKernelGGL(quant_kernel, dim3(Mpad * (D / 256) / 4), dim3(256), 0, stream,
                     x, Ntok, D, ldq1, slots + 0, 1, xq);
  hipLaunchKernelGGL(quant_kernel, dim3(H * (D / 256) / 4), dim3(256), 0, stream,
                     w1, H, D, ldq1, slots + 1, -1, wq1);
  hipLaunchKernelGGL(quant_kernel, dim3(D * (H / 256) / 4), dim3(256), 0, stream,
                     w2, D, H, ldq2, slots + 2, -1, wq2);

  // layer 1 GEMM: pure MFMA, fragment-order stores
  hipLaunchKernelGGL(gemm_frag, dim3(MT * (H / 128), 1), dim3(256), 0, stream,
                     xq, wq1, ldq1, MT, ldq1 / 64, 0, frag, 0L);

  // epilogue pass A (absmax) + pass B (quant to hq + masks) + tail fill
  hipLaunchKernelGGL(epi1max, dim3((unsigned)(NF1 / 256)), dim3(256), 0, stream,
                     frag, NF1, MT, Ntok, b1, slots);
  hipLaunchKernelGGL(epi1quant, dim3((unsigned)(NF1 / 256)), dim3(256), 0, stream,
                     frag, NF1, MT, Ntok, b1, slots, hq, ldq2, table, 12);
  hipLaunchKernelGGL(tail_fill, dim3(Mpad * 64 / 256), dim3(256), 0, stream,
                     table, 12, hq, ldq2, H);

  // layer 2 GEMM: split-K x4, fragment-order stores (reuse frag buffer)
  hipLaunchKernelGGL(gemm_frag, dim3(MT * (D / 128), SPLITK), dim3(256), 0, stream,
                     hq, wq2, ldq2, MT, (ldq2 / 64) / SPLITK, (ldq2 / 64) % SPLITK,
                     frag, CS2);

  hipLaunchKernelGGL(epi2frag, dim3((unsigned)(CS2 / 256)), dim3(256), 0, stream,
                     frag, CS2, MT, Ntok, b2, slots, out, D);
}

// Round 9
// 165.604 us; speedup vs baseline: 1.8937x; 1.8937x over previous
//
#include <hip/hip_runtime.h>
#include <hip/hip_bf16.h>
#include <stdint.h>

typedef int i32x4 __attribute__((ext_vector_type(4)));

// ---------------- exact-math helpers (match XLA/np f32 semantics) -----------

__device__ __forceinline__ float xla_erf(float x) {
#pragma clang fp contract(off)
  x = fminf(3.832506856900711f, fmaxf(-3.832506856900711f, x));
  float x2 = x * x;
  float p = -2.72614225801306e-10f;
  p = p * x2 + 2.77068142495902e-08f;
  p = p * x2 + -2.10102402082508e-06f;
  p = p * x2 + -5.69250639462346e-05f;
  p = p * x2 + -7.34990630326855e-04f;
  p = p * x2 + -2.95459980854025e-03f;
  p = p * x2 + -1.60960333262415e-02f;
  p = x * p;
  float q = -1.45660718464996e-05f;
  q = q * x2 + -2.13374055278905e-04f;
  q = q * x2 + -1.68282697438203e-03f;
  q = q * x2 + -7.37332916720468e-03f;
  q = q * x2 + -1.42647390514189e-02f;
  return p / q;
}

__device__ __forceinline__ float gelu_exact(float x) {
#pragma clang fp contract(off)
  float t = x / 1.41421356237309504880f;
  float e = xla_erf(t);
  float u = e + 1.0f;
  float v = x * u;
  return v * 0.5f;
}

__device__ __forceinline__ float epi_scale(float iacc, float sc, float b) {
#pragma clang fp contract(off)
  float v = iacc * sc;
  v = v + b;
  return v;
}

__device__ __forceinline__ int quant1(float x, float scale) {
#pragma clang fp contract(off)
  float t = x / scale;
  t = rintf(t);
  t = fmaxf(-8.0f, fminf(7.0f, t));
  return (int)t;
}

// ---------------- small kernels ---------------------------------------------

__global__ void init_kernel(unsigned* slots) {
  if (threadIdx.x < 4) slots[threadIdx.x] = 0u;
}

// block-level reduce, ONE atomic per block (same-address atomics serialize
// at ~29 cyc each — round-8 lesson)
__global__ void absmax3(const float* __restrict__ p0, long n0,
                        const float* __restrict__ p1, long n1,
                        const float* __restrict__ p2, long n2,
                        unsigned* __restrict__ slots) {
  __shared__ float red[4];
  const int t = blockIdx.y;
  const float4* p = (const float4*)(t == 0 ? p0 : (t == 1 ? p1 : p2));
  const long n4 = (t == 0 ? n0 : (t == 1 ? n1 : n2));
  float m = 0.0f;
  long i = (long)blockIdx.x * blockDim.x + threadIdx.x;
  const long stride = (long)gridDim.x * blockDim.x;
  for (; i < n4; i += stride) {
    float4 v = p[i];
    m = fmaxf(m, fmaxf(fmaxf(fabsf(v.x), fabsf(v.y)), fmaxf(fabsf(v.z), fabsf(v.w))));
  }
  for (int o = 32; o > 0; o >>= 1) m = fmaxf(m, __shfl_xor(m, o));
  if ((threadIdx.x & 63) == 0) red[threadIdx.x >> 6] = m;
  __syncthreads();
  if (threadIdx.x == 0) {
    m = fmaxf(fmaxf(red[0], red[1]), fmaxf(red[2], red[3]));
    atomicMax(slots + t, __float_as_uint(m));
  }
}

// fp32 [R][C] -> signed i8 [Rpad][ldq] (row-major); bytes [C, C+segs) hold the
// per-segment signed AND-mask (sign=-1 for weights); [C+segs, ldq) zero.
__global__ void quant_kernel(const float* __restrict__ in, int R, int C, int ldq,
                             const unsigned* __restrict__ slot, int sign,
                             char* __restrict__ qout) {
  const int segs_per_row = C >> 8;
  const int seg = blockIdx.x * 4 + (threadIdx.x >> 6);
  const int lane = threadIdx.x & 63;
  const int r = seg / segs_per_row;
  const int s = seg - r * segs_per_row;
  const float scale = fmaxf(__uint_as_float(*slot) / 7.0f, 1e-8f);
  const size_t qbase = (size_t)r * ldq + (size_t)s * 256 + lane * 4;
  int mask = 0;
  if (r < R) {
    const size_t base = (size_t)r * C + (size_t)s * 256 + lane * 4;
    float4 v = *(const float4*)(in + base);
    int q0 = quant1(v.x, scale);
    int q1 = quant1(v.y, scale);
    int q2 = quant1(v.z, scale);
    int q3 = quant1(v.w, scale);
    unsigned pk = (q0 & 0xff) | ((q1 & 0xff) << 8) | ((q2 & 0xff) << 16) |
                  ((unsigned)(q3 & 0xff) << 24);
    *(unsigned*)(qout + qbase) = pk;
    mask = q0 & q1 & q2 & q3 & 15;
  } else {
    *(unsigned*)(qout + qbase) = 0u;
    mask = 0;
  }
  for (int o = 32; o > 0; o >>= 1) mask &= __shfl_xor(mask, o);
  if (lane == 0)
    qout[(size_t)r * ldq + C + s] = (char)(sign * ((mask & 7) - (mask & 8)));
  const int padw = ldq - C - segs_per_row;
  if (s == 0 && lane < padw)
    qout[(size_t)r * ldq + C + segs_per_row + lane] = 0;
}

// ---------------- GEMM core: MFMA only, fragment-order i32x4 stores ----------
__global__ __launch_bounds__(256) void gemm_frag(
    const char* __restrict__ A, const char* __restrict__ B,
    int ldq, int mtiles, int kbase, int krem,
    i32x4* __restrict__ frag, long cslots) {
  const int tid = threadIdx.x;
  const int lane = tid & 63;
  const int wv = tid >> 6;

  // bijective XCD-aware swizzle (m204)
  const int nwg = gridDim.x;
  const int q8 = nwg >> 3, r8 = nwg & 7;
  const int xcd = blockIdx.x & 7, idx = blockIdx.x >> 3;
  const int sw = (xcd < r8 ? xcd * (q8 + 1) : r8 * (q8 + 1) + (xcd - r8) * q8) + idx;
  const int bm = sw % mtiles;
  const int bn = sw / mtiles;
  const long m0 = (long)bm * 128;
  const long n0 = (long)bn * 128;
  const int chunk = blockIdx.y;
  const int k_begin = chunk * kbase + min(chunk, krem);  // BK=64 units
  const int k_iters = kbase + (chunk < krem ? 1 : 0);

  const int wm = wv >> 1, wn = wv & 1;
  const int lr = lane & 15, kg = lane >> 4;

  const char* pA = A + (m0 + wm * 64 + lr) * (long)ldq + (long)k_begin * 64 + kg * 16;
  const char* pB = B + (n0 + wn * 64 + lr) * (long)ldq + (long)k_begin * 64 + kg * 16;
  const long fstride = 16 * (long)ldq;

  i32x4 acc[4][4] = {};

#pragma unroll 2
  for (int kt = 0; kt < k_iters; ++kt) {
    const long ko = (long)kt * 64;
    i32x4 av[4], bv[4];
#pragma unroll
    for (int f = 0; f < 4; ++f) av[f] = *(const i32x4*)(pA + f * fstride + ko);
#pragma unroll
    for (int f = 0; f < 4; ++f) bv[f] = *(const i32x4*)(pB + f * fstride + ko);
#pragma unroll
    for (int fa = 0; fa < 4; ++fa)
#pragma unroll
      for (int fb = 0; fb < 4; ++fb)
        acc[fa][fb] = __builtin_amdgcn_mfma_i32_16x16x64_i8(av[fa], bv[fb], acc[fa][fb], 0, 0, 0);
  }

  i32x4* po = frag + (long)chunk * cslots + (((long)sw * 4 + wv) * 16) * 64 + lane;
#pragma unroll
  for (int fa = 0; fa < 4; ++fa)
#pragma unroll
    for (int fb = 0; fb < 4; ++fb)
      po[(fa * 4 + fb) * 64] = acc[fa][fb];  // global_store_dwordx4, coalesced
}

// decode helper: fragment-slot t -> (m base, n); layout matches gemm_frag
struct Dec { long mb; long n; };
__device__ __forceinline__ Dec frag_decode(long t, int mtiles) {
  const int slot = (int)(t >> 12);
  const int r = (int)t & 4095;
  const int wv = r >> 10, fafb = (r >> 6) & 15, lane = r & 63;
  const int fa = fafb >> 2, fb = fafb & 3;
  const int wm = wv >> 1, wn = wv & 1;
  const int kg = lane >> 4, lr = lane & 15;
  const int bm = slot % mtiles, bn = slot / mtiles;
  Dec d;
  d.mb = (long)bm * 128 + wm * 64 + fa * 16 + kg * 4;  // rows mb..mb+3
  d.n = (long)bn * 128 + wn * 64 + fb * 16 + lr;
  return d;
}

// stage 1: grid-stride block max of |gelu(h)| -> pmax[block]  (NO atomics)
__global__ void epi1max_part(const i32x4* __restrict__ frag, long nfrag, int mtiles,
                             int Mstore, const float* __restrict__ b1,
                             const unsigned* __restrict__ slots,
                             float* __restrict__ pmax) {
  __shared__ float red[4];
  const float sa = fmaxf(__uint_as_float(slots[0]) / 7.0f, 1e-8f);
  const float sb = fmaxf(__uint_as_float(slots[1]) / 7.0f, 1e-8f);
  const float sc = sa * sb;
  float hmax = 0.0f;
  const long stride = (long)gridDim.x * 256;
  for (long t = (long)blockIdx.x * 256 + threadIdx.x; t < nfrag; t += stride) {
    Dec d = frag_decode(t, mtiles);
    i32x4 v = frag[t];
    const float b = b1[d.n];
#pragma unroll
    for (int rr = 0; rr < 4; ++rr) {
      if (d.mb + rr < Mstore) {
        float h = gelu_exact(epi_scale((float)v[rr], sc, b));
        hmax = fmaxf(hmax, fabsf(h));
      }
    }
  }
  for (int o = 32; o > 0; o >>= 1) hmax = fmaxf(hmax, __shfl_xor(hmax, o));
  if ((threadIdx.x & 63) == 0) red[threadIdx.x >> 6] = hmax;
  __syncthreads();
  if (threadIdx.x == 0)
    pmax[blockIdx.x] = fmaxf(fmaxf(red[0], red[1]), fmaxf(red[2], red[3]));
}

// stage 2: one block reduces pmax[0..n) -> slots[3] (single writer, no atomic)
__global__ void epi1max_final(const float* __restrict__ pmax, int n,
                              unsigned* __restrict__ slots) {
  __shared__ float red[4];
  float m = 0.0f;
  for (int i = threadIdx.x; i < n; i += 256) m = fmaxf(m, pmax[i]);
  for (int o = 32; o > 0; o >>= 1) m = fmaxf(m, __shfl_xor(m, o));
  if ((threadIdx.x & 63) == 0) red[threadIdx.x >> 6] = m;
  __syncthreads();
  if (threadIdx.x == 0)
    slots[3] = __float_as_uint(fmaxf(fmaxf(red[0], red[1]), fmaxf(red[2], red[3])));
}

// quantize h -> hq data columns (NO atomics, no mask work)
__global__ void epi1quant(const i32x4* __restrict__ frag, long nfrag, int mtiles,
                          int Mstore, const float* __restrict__ b1,
                          const unsigned* __restrict__ slots,
                          char* __restrict__ hq, int ldq) {
  const long t = (long)blockIdx.x * 256 + threadIdx.x;
  if (t >= nfrag) return;
  const float sa = fmaxf(__uint_as_float(slots[0]) / 7.0f, 1e-8f);
  const float sb = fmaxf(__uint_as_float(slots[1]) / 7.0f, 1e-8f);
  const float sc = sa * sb;
  const float sh = fmaxf(__uint_as_float(slots[3]) / 7.0f, 1e-8f);
  Dec d = frag_decode(t, mtiles);
  i32x4 v = frag[t];
  const float b = b1[d.n];
#pragma unroll
  for (int rr = 0; rr < 4; ++rr) {
    const long m = d.mb + rr;
    if (m < Mstore) {
      float h = gelu_exact(epi_scale((float)v[rr], sc, b));
      hq[m * (long)ldq + d.n] = (char)quant1(h, sh);
    }
  }
}

// per-(row,seg) AND-mask from hq bytes -> correction byte at hq[r][C+seg]
// one wave per (r, seg); no atomics. hq pad rows/cols pre-zeroed by memset.
__global__ void mask_fill(char* __restrict__ hq, int ldq, int C, int nseg) {
  const int wid = (blockIdx.x * 256 + threadIdx.x) >> 6;
  const int lane = threadIdx.x & 63;
  const int r = wid / nseg;
  const int seg = wid - r * nseg;
  unsigned v = *(const unsigned*)(hq + (long)r * ldq + seg * 256 + lane * 4);
  int m = (int)(v & (v >> 8) & (v >> 16) & (v >> 24)) & 15;
  for (int o = 32; o > 0; o >>= 1) m &= __shfl_xor(m, o);
  if (lane == 0)
    hq[(long)r * ldq + C + seg] = (char)((m & 7) - (m & 8));
}

// final epilogue: exact int sum of 4 split-K fragment chunks, scale+bias
__global__ void epi2frag(const i32x4* __restrict__ frag, long cslots, int mtiles,
                         int Mstore, const float* __restrict__ b2,
                         const unsigned* __restrict__ slots,
                         float* __restrict__ out, int ldo) {
  const long t = (long)blockIdx.x * 256 + threadIdx.x;
  if (t >= cslots) return;
  const float sa = fmaxf(__uint_as_float(slots[3]) / 7.0f, 1e-8f);
  const float sb = fmaxf(__uint_as_float(slots[2]) / 7.0f, 1e-8f);
  const float sc = sa * sb;
  Dec d = frag_decode(t, mtiles);
  i32x4 c0 = frag[t];
  i32x4 c1 = frag[t + cslots];
  i32x4 c2 = frag[t + 2 * cslots];
  i32x4 c3 = frag[t + 3 * cslots];
  const float b = b2[d.n];
#pragma unroll
  for (int rr = 0; rr < 4; ++rr) {
    const long m = d.mb + rr;
    if (m < Mstore) {
      int s = (c0[rr] + c1[rr]) + (c2[rr] + c3[rr]);  // exact ints
      out[m * (long)ldo + d.n] = epi_scale((float)s, sc, b);
    }
  }
}

// ---------------- launch -----------------------------------------------------

extern "C" void kernel_launch(void* const* d_in, const int* in_sizes, int n_in,
                              void* d_out, int out_size, void* d_ws, size_t ws_size,
                              hipStream_t stream) {
  const float* x  = (const float*)d_in[0];
  const float* w1 = (const float*)d_in[1];
  const float* b1 = (const float*)d_in[2];
  const float* w2 = (const float*)d_in[3];
  const float* b2 = (const float*)d_in[4];
  float* out = (float*)d_out;

  const int Ntok = 16 * 197;  // 3152
  const int Mpad = 3328;      // 26 tiles of 128
  const int D = 768, H = 3072;
  const int ldq1 = 832;       // 13 BK=64 iters
  const int ldq2 = 3136;      // 49 iters
  const int SPLITK = 4;       // 49 = 4*12 + 1
  const int MT = Mpad / 128;  // 26
  const long NF1 = (long)MT * (H / 128) * 4096;   // GEMM1 fragment lanes
  const long CS2 = (long)MT * (D / 128) * 4096;   // GEMM2 slots per chunk
  const int MAXB = 1024;      // stage-1 max blocks

  char* ws = (char*)d_ws;
  size_t o = 0;
  unsigned* slots = (unsigned*)(ws + o); o += 256;  // [x, w1, w2, h]
  float* pmax = (float*)(ws + o); o += MAXB * 4;
  char* xq  = ws + o; o += (size_t)Mpad * ldq1;
  char* wq1 = ws + o; o += (size_t)H * ldq1;
  char* wq2 = ws + o; o += (size_t)D * ldq2;
  char* hq  = ws + o; o += (size_t)Mpad * ldq2;
  o = (o + 255) & ~(size_t)255;
  i32x4* frag = (i32x4*)(ws + o); o += (size_t)NF1 * 16;  // 40.9 MB, reused by GEMM2
  (void)ws_size; (void)in_sizes; (void)n_in; (void)out_size;

  hipLaunchKernelGGL(init_kernel, dim3(1), dim3(64), 0, stream, slots);
  hipMemsetAsync(hq, 0, (size_t)Mpad * ldq2, stream);  // pad rows + tail cols

  hipLaunchKernelGGL(absmax3, dim3(512, 3), dim3(256), 0, stream,
                     x, (long)Ntok * D / 4, w1, (long)H * D / 4,
                     w2, (long)D * H / 4, slots);

  hipLaunchKernelGGL(quant_kernel, dim3(Mpad * (D / 256) / 4), dim3(256), 0, stream,
                     x, Ntok, D, ldq1, slots + 0, 1, xq);
  hipLaunchKernelGGL(quant_kernel, dim3(H * (D / 256) / 4), dim3(256), 0, stream,
                     w1, H, D, ldq1, slots + 1, -1, wq1);
  hipLaunchKernelGGL(quant_kernel, dim3(D * (H / 256) / 4), dim3(256), 0, stream,
                     w2, D, H, ldq2, slots + 2, -1, wq2);

  // layer 1 GEMM: pure MFMA, fragment-order stores
  hipLaunchKernelGGL(gemm_frag, dim3(MT * (H / 128), 1), dim3(256), 0, stream,
                     xq, wq1, ldq1, MT, ldq1 / 64, 0, frag, 0L);

  // h absmax: two-stage, atomic-free
  hipLaunchKernelGGL(epi1max_part, dim3(MAXB), dim3(256), 0, stream,
                     frag, NF1, MT, Ntok, b1, slots, pmax);
  hipLaunchKernelGGL(epi1max_final, dim3(1), dim3(256), 0, stream,
                     pmax, MAXB, slots);

  // quantize h -> hq, then fill correction masks (atomic-free)
  hipLaunchKernelGGL(epi1quant, dim3((unsigned)(NF1 / 256)), dim3(256), 0, stream,
                     frag, NF1, MT, Ntok, b1, slots, hq, ldq2);
  hipLaunchKernelGGL(mask_fill, dim3(Mpad * 12 / 4), dim3(256), 0, stream,
                     hq, ldq2, H, 12);

  // layer 2 GEMM: split-K x4, fragment-order stores (reuse frag buffer)
  hipLaunchKernelGGL(gemm_frag, dim3(MT * (D / 128), SPLITK), dim3(256), 0, stream,
                     hq, wq2, ldq2, MT, (ldq2 / 64) / SPLITK, (ldq2 / 64) % SPLITK,
                     frag, CS2);

  hipLaunchKernelGGL(epi2frag, dim3((unsigned)(CS2 / 256)), dim3(256), 0, stream,
                     frag, CS2, MT, Ntok, b2, slots, out, D);
}

// Round 10
// 149.702 us; speedup vs baseline: 2.0948x; 1.1062x over previous
//
#include <hip/hip_runtime.h>
#include <hip/hip_bf16.h>
#include <stdint.h>

typedef int i32x4 __attribute__((ext_vector_type(4)));

// ---------------- exact-math helpers (match XLA/np f32 semantics) -----------

__device__ __forceinline__ float xla_erf(float x) {
#pragma clang fp contract(off)
  x = fminf(3.832506856900711f, fmaxf(-3.832506856900711f, x));
  float x2 = x * x;
  float p = -2.72614225801306e-10f;
  p = p * x2 + 2.77068142495902e-08f;
  p = p * x2 + -2.10102402082508e-06f;
  p = p * x2 + -5.69250639462346e-05f;
  p = p * x2 + -7.34990630326855e-04f;
  p = p * x2 + -2.95459980854025e-03f;
  p = p * x2 + -1.60960333262415e-02f;
  p = x * p;
  float q = -1.45660718464996e-05f;
  q = q * x2 + -2.13374055278905e-04f;
  q = q * x2 + -1.68282697438203e-03f;
  q = q * x2 + -7.37332916720468e-03f;
  q = q * x2 + -1.42647390514189e-02f;
  return p / q;
}

__device__ __forceinline__ float gelu_exact(float x) {
#pragma clang fp contract(off)
  float t = x / 1.41421356237309504880f;
  float e = xla_erf(t);
  float u = e + 1.0f;
  float v = x * u;
  return v * 0.5f;
}

__device__ __forceinline__ float epi_scale(float iacc, float sc, float b) {
#pragma clang fp contract(off)
  float v = iacc * sc;
  v = v + b;
  return v;
}

__device__ __forceinline__ int quant1(float x, float scale) {
#pragma clang fp contract(off)
  float t = x / scale;
  t = rintf(t);
  t = fmaxf(-8.0f, fminf(7.0f, t));
  return (int)t;
}

// ---------------- small kernels ---------------------------------------------

__global__ void init_kernel(unsigned* slots) {
  if (threadIdx.x < 4) slots[threadIdx.x] = 0u;
}

// block-level reduce, ONE atomic per block (round-8 lesson: same-address
// atomics serialize ~29 cyc each)
__global__ void absmax3(const float* __restrict__ p0, long n0,
                        const float* __restrict__ p1, long n1,
                        const float* __restrict__ p2, long n2,
                        unsigned* __restrict__ slots) {
  __shared__ float red[4];
  const int t = blockIdx.y;
  const float4* p = (const float4*)(t == 0 ? p0 : (t == 1 ? p1 : p2));
  const long n4 = (t == 0 ? n0 : (t == 1 ? n1 : n2));
  float m = 0.0f;
  long i = (long)blockIdx.x * blockDim.x + threadIdx.x;
  const long stride = (long)gridDim.x * blockDim.x;
  for (; i < n4; i += stride) {
    float4 v = p[i];
    m = fmaxf(m, fmaxf(fmaxf(fabsf(v.x), fabsf(v.y)), fmaxf(fabsf(v.z), fabsf(v.w))));
  }
  for (int o = 32; o > 0; o >>= 1) m = fmaxf(m, __shfl_xor(m, o));
  if ((threadIdx.x & 63) == 0) red[threadIdx.x >> 6] = m;
  __syncthreads();
  if (threadIdx.x == 0) {
    m = fmaxf(fmaxf(red[0], red[1]), fmaxf(red[2], red[3]));
    atomicMax(slots + t, __float_as_uint(m));
  }
}

// fp32 [R][C] -> signed i8 [Rpad][ldq] (row-major); bytes [C, C+segs) hold the
// per-segment signed AND-mask (sign=-1 for weights); [C+segs, ldq) zero.
__global__ void quant_kernel(const float* __restrict__ in, int R, int C, int ldq,
                             const unsigned* __restrict__ slot, int sign,
                             char* __restrict__ qout) {
  const int segs_per_row = C >> 8;
  const int seg = blockIdx.x * 4 + (threadIdx.x >> 6);
  const int lane = threadIdx.x & 63;
  const int r = seg / segs_per_row;
  const int s = seg - r * segs_per_row;
  const float scale = fmaxf(__uint_as_float(*slot) / 7.0f, 1e-8f);
  const size_t qbase = (size_t)r * ldq + (size_t)s * 256 + lane * 4;
  int mask = 0;
  if (r < R) {
    const size_t base = (size_t)r * C + (size_t)s * 256 + lane * 4;
    float4 v = *(const float4*)(in + base);
    int q0 = quant1(v.x, scale);
    int q1 = quant1(v.y, scale);
    int q2 = quant1(v.z, scale);
    int q3 = quant1(v.w, scale);
    unsigned pk = (q0 & 0xff) | ((q1 & 0xff) << 8) | ((q2 & 0xff) << 16) |
                  ((unsigned)(q3 & 0xff) << 24);
    *(unsigned*)(qout + qbase) = pk;
    mask = q0 & q1 & q2 & q3 & 15;
  } else {
    *(unsigned*)(qout + qbase) = 0u;
    mask = 0;
  }
  for (int o = 32; o > 0; o >>= 1) mask &= __shfl_xor(mask, o);
  if (lane == 0)
    qout[(size_t)r * ldq + C + s] = (char)(sign * ((mask & 7) - (mask & 8)));
  const int padw = ldq - C - segs_per_row;
  if (s == 0 && lane < padw)
    qout[(size_t)r * ldq + C + segs_per_row + lane] = 0;
}

// ---------------- GEMM core: MFMA only, fragment-order i32x4 stores ----------
// MODE 0: additionally computes block-max of |gelu(acc*sc+b1)| -> pmax[block]
//         (plain store, no atomics) while acc is live in registers.
// MODE 1: split-K chunk partials only.
template <int MODE>
__global__ __launch_bounds__(256) void gemm_frag(
    const char* __restrict__ A, const char* __restrict__ B,
    int ldq, int mtiles, int kbase, int krem,
    i32x4* __restrict__ frag, long cslots,
    const float* __restrict__ bias, const unsigned* __restrict__ slots,
    int Mstore, float* __restrict__ pmax) {
  const int tid = threadIdx.x;
  const int lane = tid & 63;
  const int wv = tid >> 6;

  // bijective XCD-aware swizzle (m204)
  const int nwg = gridDim.x;
  const int q8 = nwg >> 3, r8 = nwg & 7;
  const int xcd = blockIdx.x & 7, idx = blockIdx.x >> 3;
  const int sw = (xcd < r8 ? xcd * (q8 + 1) : r8 * (q8 + 1) + (xcd - r8) * q8) + idx;
  const int bm = sw % mtiles;
  const int bn = sw / mtiles;
  const long m0 = (long)bm * 128;
  const long n0 = (long)bn * 128;
  const int chunk = blockIdx.y;
  const int k_begin = chunk * kbase + min(chunk, krem);  // BK=64 units
  const int k_iters = kbase + (chunk < krem ? 1 : 0);

  const int wm = wv >> 1, wn = wv & 1;
  const int lr = lane & 15, kg = lane >> 4;

  const char* pA = A + (m0 + wm * 64 + lr) * (long)ldq + (long)k_begin * 64 + kg * 16;
  const char* pB = B + (n0 + wn * 64 + lr) * (long)ldq + (long)k_begin * 64 + kg * 16;
  const long fstride = 16 * (long)ldq;

  i32x4 acc[4][4] = {};

#pragma unroll 2
  for (int kt = 0; kt < k_iters; ++kt) {
    const long ko = (long)kt * 64;
    i32x4 av[4], bv[4];
#pragma unroll
    for (int f = 0; f < 4; ++f) av[f] = *(const i32x4*)(pA + f * fstride + ko);
#pragma unroll
    for (int f = 0; f < 4; ++f) bv[f] = *(const i32x4*)(pB + f * fstride + ko);
#pragma unroll
    for (int fa = 0; fa < 4; ++fa)
#pragma unroll
      for (int fb = 0; fb < 4; ++fb)
        acc[fa][fb] = __builtin_amdgcn_mfma_i32_16x16x64_i8(av[fa], bv[fb], acc[fa][fb], 0, 0, 0);
  }

  i32x4* po = frag + (long)chunk * cslots + (((long)sw * 4 + wv) * 16) * 64 + lane;
#pragma unroll
  for (int fa = 0; fa < 4; ++fa)
#pragma unroll
    for (int fb = 0; fb < 4; ++fb)
      po[(fa * 4 + fb) * 64] = acc[fa][fb];  // global_store_dwordx4, coalesced

  if (MODE == 0) {
    __shared__ float red[4];
    const float sa = fmaxf(__uint_as_float(slots[0]) / 7.0f, 1e-8f);
    const float sb = fmaxf(__uint_as_float(slots[1]) / 7.0f, 1e-8f);
    const float sc = sa * sb;
    float bl[4];
#pragma unroll
    for (int fb = 0; fb < 4; ++fb) bl[fb] = bias[n0 + wn * 64 + fb * 16 + lr];
    float hmax = 0.0f;
#pragma unroll
    for (int fa = 0; fa < 4; ++fa) {
#pragma unroll
      for (int rr = 0; rr < 4; ++rr) {
        const long m = m0 + wm * 64 + fa * 16 + kg * 4 + rr;
        if (m < Mstore) {
#pragma unroll
          for (int fb = 0; fb < 4; ++fb) {
            float h = gelu_exact(epi_scale((float)acc[fa][fb][rr], sc, bl[fb]));
            hmax = fmaxf(hmax, fabsf(h));
          }
        }
      }
    }
    for (int o = 32; o > 0; o >>= 1) hmax = fmaxf(hmax, __shfl_xor(hmax, o));
    if ((tid & 63) == 0) red[tid >> 6] = hmax;
    __syncthreads();
    if (tid == 0)
      pmax[blockIdx.x] = fmaxf(fmaxf(red[0], red[1]), fmaxf(red[2], red[3]));
  }
}

// one block reduces pmax[0..n) -> slots[3] (single writer, no atomic)
__global__ void epi1max_final(const float* __restrict__ pmax, int n,
                              unsigned* __restrict__ slots) {
  __shared__ float red[4];
  float m = 0.0f;
  for (int i = threadIdx.x; i < n; i += 256) m = fmaxf(m, pmax[i]);
  for (int o = 32; o > 0; o >>= 1) m = fmaxf(m, __shfl_xor(m, o));
  if ((threadIdx.x & 63) == 0) red[threadIdx.x >> 6] = m;
  __syncthreads();
  if (threadIdx.x == 0)
    slots[3] = __float_as_uint(fmaxf(fmaxf(red[0], red[1]), fmaxf(red[2], red[3])));
}

// decode helper: fragment-slot t -> (m base, n); layout matches gemm_frag
struct Dec { long mb; long n; };
__device__ __forceinline__ Dec frag_decode(long t, int mtiles) {
  const int slot = (int)(t >> 12);
  const int r = (int)t & 4095;
  const int wv = r >> 10, fafb = (r >> 6) & 15, lane = r & 63;
  const int fa = fafb >> 2, fb = fafb & 3;
  const int wm = wv >> 1, wn = wv & 1;
  const int kg = lane >> 4, lr = lane & 15;
  const int bm = slot % mtiles, bn = slot / mtiles;
  Dec d;
  d.mb = (long)bm * 128 + wm * 64 + fa * 16 + kg * 4;  // rows mb..mb+3
  d.n = (long)bn * 128 + wn * 64 + fb * 16 + lr;
  return d;
}

// quantize h -> hq data columns; pad rows (m >= Mstore) get explicit zeros
// (replaces the 42us fillBuffer memset). No atomics.
__global__ void epi1quant(const i32x4* __restrict__ frag, long nfrag, int mtiles,
                          int Mstore, const float* __restrict__ b1,
                          const unsigned* __restrict__ slots,
                          char* __restrict__ hq, int ldq) {
  const long t = (long)blockIdx.x * 256 + threadIdx.x;
  if (t >= nfrag) return;
  const float sa = fmaxf(__uint_as_float(slots[0]) / 7.0f, 1e-8f);
  const float sb = fmaxf(__uint_as_float(slots[1]) / 7.0f, 1e-8f);
  const float sc = sa * sb;
  const float sh = fmaxf(__uint_as_float(slots[3]) / 7.0f, 1e-8f);
  Dec d = frag_decode(t, mtiles);
  i32x4 v = frag[t];
  const float b = b1[d.n];
#pragma unroll
  for (int rr = 0; rr < 4; ++rr) {
    const long m = d.mb + rr;
    char q = 0;
    if (m < Mstore) {
      float h = gelu_exact(epi_scale((float)v[rr], sc, b));
      q = (char)quant1(h, sh);
    }
    hq[m * (long)ldq + d.n] = q;  // m < Mpad always (frag covers all rows)
  }
}

// one block per row: per-seg AND-masks -> hq[r][C+seg], zero tail [C+12,C+64).
// wave w reduces segs {w, w+4, w+8} (64 u32 per seg). No atomics, no memset.
__global__ void mask_fill(char* __restrict__ hq, int ldq, int C, int nseg) {
  const long r = blockIdx.x;
  const int tid = threadIdx.x;
  const int lane = tid & 63, w = tid >> 6;
  const unsigned* row = (const unsigned*)(hq + r * ldq);
  int mk[3];
#pragma unroll
  for (int j = 0; j < 3; ++j) {
    unsigned v = row[tid + j * 256];
    mk[j] = (int)(v & (v >> 8) & (v >> 16) & (v >> 24)) & 15;
  }
#pragma unroll
  for (int j = 0; j < 3; ++j)
    for (int o = 32; o > 0; o >>= 1) mk[j] &= __shfl_xor(mk[j], o);
  if (lane == 0) {
#pragma unroll
    for (int j = 0; j < 3; ++j) {
      const int seg = j * 4 + w;
      hq[r * ldq + C + seg] = (char)((mk[j] & 7) - (mk[j] & 8));
    }
  }
  if (tid >= nseg && tid < 64) hq[r * ldq + C + tid] = 0;  // zero tail
}

// final epilogue: exact int sum of 4 split-K fragment chunks, scale+bias
__global__ void epi2frag(const i32x4* __restrict__ frag, long cslots, int mtiles,
                         int Mstore, const float* __restrict__ b2,
                         const unsigned* __restrict__ slots,
                         float* __restrict__ out, int ldo) {
  const long t = (long)blockIdx.x * 256 + threadIdx.x;
  if (t >= cslots) return;
  const float sa = fmaxf(__uint_as_float(slots[3]) / 7.0f, 1e-8f);
  const float sb = fmaxf(__uint_as_float(slots[2]) / 7.0f, 1e-8f);
  const float sc = sa * sb;
  Dec d = frag_decode(t, mtiles);
  i32x4 c0 = frag[t];
  i32x4 c1 = frag[t + cslots];
  i32x4 c2 = frag[t + 2 * cslots];
  i32x4 c3 = frag[t + 3 * cslots];
  const float b = b2[d.n];
#pragma unroll
  for (int rr = 0; rr < 4; ++rr) {
    const long m = d.mb + rr;
    if (m < Mstore) {
      int s = (c0[rr] + c1[rr]) + (c2[rr] + c3[rr]);  // exact ints
      out[m * (long)ldo + d.n] = epi_scale((float)s, sc, b);
    }
  }
}

// ---------------- launch -----------------------------------------------------

extern "C" void kernel_launch(void* const* d_in, const int* in_sizes, int n_in,
                              void* d_out, int out_size, void* d_ws, size_t ws_size,
                              hipStream_t stream) {
  const float* x  = (const float*)d_in[0];
  const float* w1 = (const float*)d_in[1];
  const float* b1 = (const float*)d_in[2];
  const float* w2 = (const float*)d_in[3];
  const float* b2 = (const float*)d_in[4];
  float* out = (float*)d_out;

  const int Ntok = 16 * 197;  // 3152
  const int Mpad = 3328;      // 26 tiles of 128
  const int D = 768, H = 3072;
  const int ldq1 = 832;       // 13 BK=64 iters
  const int ldq2 = 3136;      // 49 iters
  const int SPLITK = 4;       // 49 = 4*12 + 1
  const int MT = Mpad / 128;  // 26
  const int NB1 = MT * (H / 128);                 // 624 gemm1 blocks
  const long NF1 = (long)NB1 * 4096;              // GEMM1 fragment lanes
  const long CS2 = (long)MT * (D / 128) * 4096;   // GEMM2 slots per chunk

  char* ws = (char*)d_ws;
  size_t o = 0;
  unsigned* slots = (unsigned*)(ws + o); o += 256;  // [x, w1, w2, h]
  float* pmax = (float*)(ws + o); o += 4096;
  char* xq  = ws + o; o += (size_t)Mpad * ldq1;
  char* wq1 = ws + o; o += (size_t)H * ldq1;
  char* wq2 = ws + o; o += (size_t)D * ldq2;
  char* hq  = ws + o; o += (size_t)Mpad * ldq2;
  o = (o + 255) & ~(size_t)255;
  i32x4* frag = (i32x4*)(ws + o); o += (size_t)NF1 * 16;  // 40.9 MB, reused by GEMM2
  (void)ws_size; (void)in_sizes; (void)n_in; (void)out_size;

  hipLaunchKernelGGL(init_kernel, dim3(1), dim3(64), 0, stream, slots);

  hipLaunchKernelGGL(absmax3, dim3(512, 3), dim3(256), 0, stream,
                     x, (long)Ntok * D / 4, w1, (long)H * D / 4,
                     w2, (long)D * H / 4, slots);

  hipLaunchKernelGGL(quant_kernel, dim3(Mpad * (D / 256) / 4), dim3(256), 0, stream,
                     x, Ntok, D, ldq1, slots + 0, 1, xq);
  hipLaunchKernelGGL(quant_kernel, dim3(H * (D / 256) / 4), dim3(256), 0, stream,
                     w1, H, D, ldq1, slots + 1, -1, wq1);
  hipLaunchKernelGGL(quant_kernel, dim3(D * (H / 256) / 4), dim3(256), 0, stream,
                     w2, D, H, ldq2, slots + 2, -1, wq2);

  // layer 1 GEMM: fragment stores + fused block-max of gelu(h) -> pmax
  hipLaunchKernelGGL((gemm_frag<0>), dim3(NB1, 1), dim3(256), 0, stream,
                     xq, wq1, ldq1, MT, ldq1 / 64, 0, frag, 0L,
                     b1, slots, Ntok, pmax);
  hipLaunchKernelGGL(epi1max_final, dim3(1), dim3(256), 0, stream,
                     pmax, NB1, slots);

  // quantize h -> hq (pad rows zeroed inline), then masks + tail (atomic-free)
  hipLaunchKernelGGL(epi1quant, dim3((unsigned)(NF1 / 256)), dim3(256), 0, stream,
                     frag, NF1, MT, Ntok, b1, slots, hq, ldq2);
  hipLaunchKernelGGL(mask_fill, dim3(Mpad), dim3(256), 0, stream,
                     hq, ldq2, H, 12);

  // layer 2 GEMM: split-K x4, fragment-order stores (reuse frag buffer)
  hipLaunchKernelGGL((gemm_frag<1>), dim3(MT * (D / 128), SPLITK), dim3(256), 0, stream,
                     hq, wq2, ldq2, MT, (ldq2 / 64) / SPLITK, (ldq2 / 64) % SPLITK,
                     frag, CS2, nullptr, nullptr, 0, nullptr);

  hipLaunchKernelGGL(epi2frag, dim3((unsigned)(CS2 / 256)), dim3(256), 0, stream,
                     frag, CS2, MT, Ntok, b2, slots, out, D);
}

// Round 11
// 142.933 us; speedup vs baseline: 2.1940x; 1.0474x over previous
//
#include <hip/hip_runtime.h>
#include <hip/hip_bf16.h>
#include <stdint.h>

typedef int i32x4 __attribute__((ext_vector_type(4)));

// ---------------- exact-math helpers (match XLA/np f32 semantics) -----------

__device__ __forceinline__ float xla_erf(float x) {
#pragma clang fp contract(off)
  x = fminf(3.832506856900711f, fmaxf(-3.832506856900711f, x));
  float x2 = x * x;
  float p = -2.72614225801306e-10f;
  p = p * x2 + 2.77068142495902e-08f;
  p = p * x2 + -2.10102402082508e-06f;
  p = p * x2 + -5.69250639462346e-05f;
  p = p * x2 + -7.34990630326855e-04f;
  p = p * x2 + -2.95459980854025e-03f;
  p = p * x2 + -1.60960333262415e-02f;
  p = x * p;
  float q = -1.45660718464996e-05f;
  q = q * x2 + -2.13374055278905e-04f;
  q = q * x2 + -1.68282697438203e-03f;
  q = q * x2 + -7.37332916720468e-03f;
  q = q * x2 + -1.42647390514189e-02f;
  return p / q;
}

__device__ __forceinline__ float gelu_exact(float x) {
#pragma clang fp contract(off)
  float t = x / 1.41421356237309504880f;
  float e = xla_erf(t);
  float u = e + 1.0f;
  float v = x * u;
  return v * 0.5f;
}

__device__ __forceinline__ float epi_scale(float iacc, float sc, float b) {
#pragma clang fp contract(off)
  float v = iacc * sc;
  v = v + b;
  return v;
}

__device__ __forceinline__ int quant1(float x, float scale) {
#pragma clang fp contract(off)
  float t = x / scale;
  t = rintf(t);
  t = fmaxf(-8.0f, fminf(7.0f, t));
  return (int)t;
}

// ---------------- small kernels ---------------------------------------------

__global__ void init_kernel(unsigned* slots) {
  if (threadIdx.x < 4) slots[threadIdx.x] = 0u;
}

// block-level reduce, ONE atomic per block (round-8 lesson)
__global__ void absmax3(const float* __restrict__ p0, long n0,
                        const float* __restrict__ p1, long n1,
                        const float* __restrict__ p2, long n2,
                        unsigned* __restrict__ slots) {
  __shared__ float red[4];
  const int t = blockIdx.y;
  const float4* p = (const float4*)(t == 0 ? p0 : (t == 1 ? p1 : p2));
  const long n4 = (t == 0 ? n0 : (t == 1 ? n1 : n2));
  float m = 0.0f;
  long i = (long)blockIdx.x * blockDim.x + threadIdx.x;
  const long stride = (long)gridDim.x * blockDim.x;
  for (; i < n4; i += stride) {
    float4 v = p[i];
    m = fmaxf(m, fmaxf(fmaxf(fabsf(v.x), fabsf(v.y)), fmaxf(fabsf(v.z), fabsf(v.w))));
  }
  for (int o = 32; o > 0; o >>= 1) m = fmaxf(m, __shfl_xor(m, o));
  if ((threadIdx.x & 63) == 0) red[threadIdx.x >> 6] = m;
  __syncthreads();
  if (threadIdx.x == 0) {
    m = fmaxf(fmaxf(red[0], red[1]), fmaxf(red[2], red[3]));
    atomicMax(slots + t, __float_as_uint(m));
  }
}

// fp32 [R][C] -> signed i8 [Rpad][ldq] (row-major); bytes [C, C+segs) hold the
// per-segment signed AND-mask (sign=-1 for weights); [C+segs, ldq) zero.
__global__ void quant_kernel(const float* __restrict__ in, int R, int C, int ldq,
                             const unsigned* __restrict__ slot, int sign,
                             char* __restrict__ qout) {
  const int segs_per_row = C >> 8;
  const int seg = blockIdx.x * 4 + (threadIdx.x >> 6);
  const int lane = threadIdx.x & 63;
  const int r = seg / segs_per_row;
  const int s = seg - r * segs_per_row;
  const float scale = fmaxf(__uint_as_float(*slot) / 7.0f, 1e-8f);
  const size_t qbase = (size_t)r * ldq + (size_t)s * 256 + lane * 4;
  int mask = 0;
  if (r < R) {
    const size_t base = (size_t)r * C + (size_t)s * 256 + lane * 4;
    float4 v = *(const float4*)(in + base);
    int q0 = quant1(v.x, scale);
    int q1 = quant1(v.y, scale);
    int q2 = quant1(v.z, scale);
    int q3 = quant1(v.w, scale);
    unsigned pk = (q0 & 0xff) | ((q1 & 0xff) << 8) | ((q2 & 0xff) << 16) |
                  ((unsigned)(q3 & 0xff) << 24);
    *(unsigned*)(qout + qbase) = pk;
    mask = q0 & q1 & q2 & q3 & 15;
  } else {
    *(unsigned*)(qout + qbase) = 0u;
    mask = 0;
  }
  for (int o = 32; o > 0; o >>= 1) mask &= __shfl_xor(mask, o);
  if (lane == 0)
    qout[(size_t)r * ldq + C + s] = (char)(sign * ((mask & 7) - (mask & 8)));
  const int padw = ldq - C - segs_per_row;
  if (s == 0 && lane < padw)
    qout[(size_t)r * ldq + C + segs_per_row + lane] = 0;
}

// repack row-major [Rpad][ldq] i8 -> fragment-tiled [Rpad/16][ldq/64][64][16]:
// tile t=(rt,kt), lane l holds row rt*16+(l&15), k bytes kt*64+(l>>4)*16 ..+16.
// One wave per 1KB tile: scattered 16B reads (paid once), contiguous 1KB write.
__global__ void repack_kernel(const char* __restrict__ in, char* __restrict__ out,
                              int ldq, int ktiles, int ntiles) {
  const int wid = (int)((blockIdx.x * 256 + threadIdx.x) >> 6);
  const int lane = threadIdx.x & 63;
  if (wid >= ntiles) return;
  const int rt = wid / ktiles, kt = wid - rt * ktiles;
  const int lr = lane & 15, kg = lane >> 4;
  i32x4 v = *(const i32x4*)(in + ((long)rt * 16 + lr) * ldq + kt * 64 + kg * 16);
  *(i32x4*)(out + (long)wid * 1024 + lane * 16) = v;
}

// ---------------- GEMM core: fragment-tiled inputs, fragment-order stores ----
// All loads AND stores are lane-contiguous 1KB bursts. Register-direct, no
// LDS, no barriers. MODE 0: fused block-max of |gelu(acc*sc+b1)| -> pmax.
// MODE 1: split-K chunk partials only.
template <int MODE>
__global__ __launch_bounds__(256) void gemm_frag(
    const char* __restrict__ A, const char* __restrict__ B,
    int ldq, int mtiles, int kbase, int krem,
    i32x4* __restrict__ frag, long cslots,
    const float* __restrict__ bias, const unsigned* __restrict__ slots,
    int Mstore, float* __restrict__ pmax) {
  const int tid = threadIdx.x;
  const int lane = tid & 63;
  const int wv = tid >> 6;

  // bijective XCD-aware swizzle (m204)
  const int nwg = gridDim.x;
  const int q8 = nwg >> 3, r8 = nwg & 7;
  const int xcd = blockIdx.x & 7, idx = blockIdx.x >> 3;
  const int sw = (xcd < r8 ? xcd * (q8 + 1) : r8 * (q8 + 1) + (xcd - r8) * q8) + idx;
  const int bm = sw % mtiles;
  const int bn = sw / mtiles;
  const long m0 = (long)bm * 128;
  const long n0 = (long)bn * 128;
  const int chunk = blockIdx.y;
  const int k_begin = chunk * kbase + min(chunk, krem);  // BK=64 tile units
  const int k_iters = kbase + (chunk < krem ? 1 : 0);

  const int wm = wv >> 1, wn = wv & 1;
  const int lr = lane & 15, kg = lane >> 4;
  const int ktA = ldq >> 6;  // k-tiles per row-tile

  const char* pA = A + (((long)(m0 >> 4) + wm * 4) * ktA + k_begin) * 1024 + lane * 16;
  const char* pB = B + (((long)(n0 >> 4) + wn * 4) * ktA + k_begin) * 1024 + lane * 16;
  const long fstr = (long)ktA * 1024;

  i32x4 acc[4][4] = {};

#pragma unroll 2
  for (int kt = 0; kt < k_iters; ++kt) {
    const long ko = (long)kt * 1024;
    i32x4 av[4], bv[4];
#pragma unroll
    for (int f = 0; f < 4; ++f) av[f] = *(const i32x4*)(pA + f * fstr + ko);
#pragma unroll
    for (int f = 0; f < 4; ++f) bv[f] = *(const i32x4*)(pB + f * fstr + ko);
#pragma unroll
    for (int fa = 0; fa < 4; ++fa)
#pragma unroll
      for (int fb = 0; fb < 4; ++fb)
        acc[fa][fb] = __builtin_amdgcn_mfma_i32_16x16x64_i8(av[fa], bv[fb], acc[fa][fb], 0, 0, 0);
  }

  i32x4* po = frag + (long)chunk * cslots + (((long)sw * 4 + wv) * 16) * 64 + lane;
#pragma unroll
  for (int fa = 0; fa < 4; ++fa)
#pragma unroll
    for (int fb = 0; fb < 4; ++fb)
      po[(fa * 4 + fb) * 64] = acc[fa][fb];  // coalesced 1KB bursts

  if (MODE == 0) {
    __shared__ float red[4];
    const float sa = fmaxf(__uint_as_float(slots[0]) / 7.0f, 1e-8f);
    const float sb = fmaxf(__uint_as_float(slots[1]) / 7.0f, 1e-8f);
    const float sc = sa * sb;
    float bl[4];
#pragma unroll
    for (int fb = 0; fb < 4; ++fb) bl[fb] = bias[n0 + wn * 64 + fb * 16 + lr];
    float hmax = 0.0f;
#pragma unroll
    for (int fa = 0; fa < 4; ++fa) {
#pragma unroll
      for (int rr = 0; rr < 4; ++rr) {
        const long m = m0 + wm * 64 + fa * 16 + kg * 4 + rr;
        if (m < Mstore) {
#pragma unroll
          for (int fb = 0; fb < 4; ++fb) {
            float h = gelu_exact(epi_scale((float)acc[fa][fb][rr], sc, bl[fb]));
            hmax = fmaxf(hmax, fabsf(h));
          }
        }
      }
    }
    for (int o = 32; o > 0; o >>= 1) hmax = fmaxf(hmax, __shfl_xor(hmax, o));
    if ((tid & 63) == 0) red[tid >> 6] = hmax;
    __syncthreads();
    if (tid == 0)
      pmax[blockIdx.x] = fmaxf(fmaxf(red[0], red[1]), fmaxf(red[2], red[3]));
  }
}

// one block reduces pmax[0..n) -> slots[3] (single writer, no atomic)
__global__ void epi1max_final(const float* __restrict__ pmax, int n,
                              unsigned* __restrict__ slots) {
  __shared__ float red[4];
  float m = 0.0f;
  for (int i = threadIdx.x; i < n; i += 256) m = fmaxf(m, pmax[i]);
  for (int o = 32; o > 0; o >>= 1) m = fmaxf(m, __shfl_xor(m, o));
  if ((threadIdx.x & 63) == 0) red[threadIdx.x >> 6] = m;
  __syncthreads();
  if (threadIdx.x == 0)
    slots[3] = __float_as_uint(fmaxf(fmaxf(red[0], red[1]), fmaxf(red[2], red[3])));
}

// decode helper: fragment-slot t -> (m base, n); layout matches gemm_frag
struct Dec { long mb; long n; };
__device__ __forceinline__ Dec frag_decode(long t, int mtiles) {
  const int slot = (int)(t >> 12);
  const int r = (int)t & 4095;
  const int wv = r >> 10, fafb = (r >> 6) & 15, lane = r & 63;
  const int fa = fafb >> 2, fb = fafb & 3;
  const int wm = wv >> 1, wn = wv & 1;
  const int kg = lane >> 4, lr = lane & 15;
  const int bm = slot % mtiles, bn = slot / mtiles;
  Dec d;
  d.mb = (long)bm * 128 + wm * 64 + fa * 16 + kg * 4;  // rows mb..mb+3
  d.n = (long)bn * 128 + wn * 64 + fb * 16 + lr;
  return d;
}

// quantize h -> hq data columns; pad rows get explicit zeros. No atomics.
__global__ void epi1quant(const i32x4* __restrict__ frag, long nfrag, int mtiles,
                          int Mstore, const float* __restrict__ b1,
                          const unsigned* __restrict__ slots,
                          char* __restrict__ hq, int ldq) {
  const long t = (long)blockIdx.x * 256 + threadIdx.x;
  if (t >= nfrag) return;
  const float sa = fmaxf(__uint_as_float(slots[0]) / 7.0f, 1e-8f);
  const float sb = fmaxf(__uint_as_float(slots[1]) / 7.0f, 1e-8f);
  const float sc = sa * sb;
  const float sh = fmaxf(__uint_as_float(slots[3]) / 7.0f, 1e-8f);
  Dec d = frag_decode(t, mtiles);
  i32x4 v = frag[t];
  const float b = b1[d.n];
#pragma unroll
  for (int rr = 0; rr < 4; ++rr) {
    const long m = d.mb + rr;
    char q = 0;
    if (m < Mstore) {
      float h = gelu_exact(epi_scale((float)v[rr], sc, b));
      q = (char)quant1(h, sh);
    }
    hq[m * (long)ldq + d.n] = q;
  }
}

// one block per row: per-seg AND-masks -> hq[r][C+seg], zero tail [C+12,C+64).
__global__ void mask_fill(char* __restrict__ hq, int ldq, int C, int nseg) {
  const long r = blockIdx.x;
  const int tid = threadIdx.x;
  const int lane = tid & 63, w = tid >> 6;
  const unsigned* row = (const unsigned*)(hq + r * ldq);
  int mk[3];
#pragma unroll
  for (int j = 0; j < 3; ++j) {
    unsigned v = row[tid + j * 256];
    mk[j] = (int)(v & (v >> 8) & (v >> 16) & (v >> 24)) & 15;
  }
#pragma unroll
  for (int j = 0; j < 3; ++j)
    for (int o = 32; o > 0; o >>= 1) mk[j] &= __shfl_xor(mk[j], o);
  if (lane == 0) {
#pragma unroll
    for (int j = 0; j < 3; ++j) {
      const int seg = j * 4 + w;
      hq[r * ldq + C + seg] = (char)((mk[j] & 7) - (mk[j] & 8));
    }
  }
  if (tid >= nseg && tid < 64) hq[r * ldq + C + tid] = 0;  // zero tail
}

// final epilogue: exact int sum of 4 split-K fragment chunks, scale+bias
__global__ void epi2frag(const i32x4* __restrict__ frag, long cslots, int mtiles,
                         int Mstore, const float* __restrict__ b2,
                         const unsigned* __restrict__ slots,
                         float* __restrict__ out, int ldo) {
  const long t = (long)blockIdx.x * 256 + threadIdx.x;
  if (t >= cslots) return;
  const float sa = fmaxf(__uint_as_float(slots[3]) / 7.0f, 1e-8f);
  const float sb = fmaxf(__uint_as_float(slots[2]) / 7.0f, 1e-8f);
  const float sc = sa * sb;
  Dec d = frag_decode(t, mtiles);
  i32x4 c0 = frag[t];
  i32x4 c1 = frag[t + cslots];
  i32x4 c2 = frag[t + 2 * cslots];
  i32x4 c3 = frag[t + 3 * cslots];
  const float b = b2[d.n];
#pragma unroll
  for (int rr = 0; rr < 4; ++rr) {
    const long m = d.mb + rr;
    if (m < Mstore) {
      int s = (c0[rr] + c1[rr]) + (c2[rr] + c3[rr]);  // exact ints
      out[m * (long)ldo + d.n] = epi_scale((float)s, sc, b);
    }
  }
}

// ---------------- launch -----------------------------------------------------

extern "C" void kernel_launch(void* const* d_in, const int* in_sizes, int n_in,
                              void* d_out, int out_size, void* d_ws, size_t ws_size,
                              hipStream_t stream) {
  const float* x  = (const float*)d_in[0];
  const float* w1 = (const float*)d_in[1];
  const float* b1 = (const float*)d_in[2];
  const float* w2 = (const float*)d_in[3];
  const float* b2 = (const float*)d_in[4];
  float* out = (float*)d_out;

  const int Ntok = 16 * 197;  // 3152
  const int Mpad = 3328;      // 26 tiles of 128
  const int D = 768, H = 3072;
  const int ldq1 = 832;       // 13 k-tiles
  const int ldq2 = 3136;      // 49 k-tiles
  const int SPLITK = 4;       // 49 = 4*12 + 1
  const int MT = Mpad / 128;  // 26
  const int NB1 = MT * (H / 128);                 // 624 gemm1 blocks
  const long NF1 = (long)NB1 * 4096;              // GEMM1 fragment lanes
  const long CS2 = (long)MT * (D / 128) * 4096;   // GEMM2 slots per chunk
  const int NT_XQ  = (Mpad / 16) * (ldq1 / 64);   // 2704 tiles
  const int NT_WQ1 = (H / 16) * (ldq1 / 64);      // 2496
  const int NT_WQ2 = (D / 16) * (ldq2 / 64);      // 2352
  const int NT_HQ  = (Mpad / 16) * (ldq2 / 64);   // 10192

  char* ws = (char*)d_ws;
  size_t o = 0;
  unsigned* slots = (unsigned*)(ws + o); o += 256;  // [x, w1, w2, h]
  float* pmax = (float*)(ws + o); o += 4096;
  char* xq  = ws + o; o += (size_t)Mpad * ldq1;
  char* wq1 = ws + o; o += (size_t)H * ldq1;
  char* wq2 = ws + o; o += (size_t)D * ldq2;
  char* hq  = ws + o; o += (size_t)Mpad * ldq2;
  o = (o + 1023) & ~(size_t)1023;
  char* xqt  = ws + o; o += (size_t)NT_XQ * 1024;
  char* wq1t = ws + o; o += (size_t)NT_WQ1 * 1024;
  char* wq2t = ws + o; o += (size_t)NT_WQ2 * 1024;
  char* hqt  = ws + o; o += (size_t)NT_HQ * 1024;
  o = (o + 1023) & ~(size_t)1023;
  i32x4* frag = (i32x4*)(ws + o); o += (size_t)NF1 * 16;  // 40.9 MB
  (void)ws_size; (void)in_sizes; (void)n_in; (void)out_size;

  hipLaunchKernelGGL(init_kernel, dim3(1), dim3(64), 0, stream, slots);

  hipLaunchKernelGGL(absmax3, dim3(512, 3), dim3(256), 0, stream,
                     x, (long)Ntok * D / 4, w1, (long)H * D / 4,
                     w2, (long)D * H / 4, slots);

  hipLaunchKernelGGL(quant_kernel, dim3(Mpad * (D / 256) / 4), dim3(256), 0, stream,
                     x, Ntok, D, ldq1, slots + 0, 1, xq);
  hipLaunchKernelGGL(quant_kernel, dim3(H * (D / 256) / 4), dim3(256), 0, stream,
                     w1, H, D, ldq1, slots + 1, -1, wq1);
  hipLaunchKernelGGL(quant_kernel, dim3(D * (H / 256) / 4), dim3(256), 0, stream,
                     w2, D, H, ldq2, slots + 2, -1, wq2);

  // repack to fragment-major (lane-contiguous GEMM loads)
  hipLaunchKernelGGL(repack_kernel, dim3(NT_XQ / 4), dim3(256), 0, stream,
                     xq, xqt, ldq1, ldq1 / 64, NT_XQ);
  hipLaunchKernelGGL(repack_kernel, dim3(NT_WQ1 / 4), dim3(256), 0, stream,
                     wq1, wq1t, ldq1, ldq1 / 64, NT_WQ1);
  hipLaunchKernelGGL(repack_kernel, dim3(NT_WQ2 / 4), dim3(256), 0, stream,
                     wq2, wq2t, ldq2, ldq2 / 64, NT_WQ2);

  // layer 1 GEMM: fragment stores + fused block-max of gelu(h) -> pmax
  hipLaunchKernelGGL((gemm_frag<0>), dim3(NB1, 1), dim3(256), 0, stream,
                     xqt, wq1t, ldq1, MT, ldq1 / 64, 0, frag, 0L,
                     b1, slots, Ntok, pmax);
  hipLaunchKernelGGL(epi1max_final, dim3(1), dim3(256), 0, stream,
                     pmax, NB1, slots);

  // quantize h -> hq (pad rows zeroed inline), masks + tail, repack
  hipLaunchKernelGGL(epi1quant, dim3((unsigned)(NF1 / 256)), dim3(256), 0, stream,
                     frag, NF1, MT, Ntok, b1, slots, hq, ldq2);
  hipLaunchKernelGGL(mask_fill, dim3(Mpad), dim3(256), 0, stream,
                     hq, ldq2, H, 12);
  hipLaunchKernelGGL(repack_kernel, dim3(NT_HQ / 4), dim3(256), 0, stream,
                     hq, hqt, ldq2, ldq2 / 64, NT_HQ);

  // layer 2 GEMM: split-K x4, fragment-order stores (reuse frag buffer)
  hipLaunchKernelGGL((gemm_frag<1>), dim3(MT * (D / 128), SPLITK), dim3(256), 0, stream,
                     hqt, wq2t, ldq2, MT, (ldq2 / 64) / SPLITK, (ldq2 / 64) % SPLITK,
                     frag, CS2, nullptr, nullptr, 0, nullptr);

  hipLaunchKernelGGL(epi2frag, dim3((unsigned)(CS2 / 256)), dim3(256), 0, stream,
                     frag, CS2, MT, Ntok, b2, slots, out, D);
}